// Round 1
// baseline (4350.987 us; speedup 1.0000x reference)
//
#include <hip/hip_runtime.h>
#include <hip/hip_bf16.h>

#define T_ 64
#define B_ 64
#define E_ 512
#define H_ 1024
#define V_ 10000
#define TB 4096  // T_*B_

typedef unsigned short u16;
typedef __attribute__((ext_vector_type(8))) short short8v;
typedef __attribute__((ext_vector_type(4))) float f32x4;

__device__ inline f32x4 mfma_bf16(short8v a, short8v b, f32x4 c) {
  return __builtin_amdgcn_mfma_f32_16x16x32_bf16(a, b, c, 0, 0, 0);
}

__device__ inline u16 f2bf(float f) {
  unsigned u = __float_as_uint(f);
  unsigned r = (u + 0x7fffu + ((u >> 16) & 1u)) >> 16;
  return (u16)r;
}
__device__ inline float bf2f(u16 h) { return __uint_as_float(((unsigned)h) << 16); }

// ---------------- prep kernels ----------------

__global__ void k_f2bf(const float* __restrict__ src, u16* __restrict__ dst, int n) {
  int i = blockIdx.x * 256 + threadIdx.x;
  int stride = gridDim.x * 256;
  for (; i < n; i += stride) dst[i] = f2bf(src[i]);
}

__global__ void k_gather(const int* __restrict__ idx, const float* __restrict__ emb,
                         u16* __restrict__ xbf) {
  int i = blockIdx.x * 256 + threadIdx.x;  // over TB*E_
  int row = i >> 9, e = i & 511;
  xbf[i] = f2bf(emb[(size_t)idx[row] * E_ + e]);
}

__global__ void k_bias(const float* __restrict__ bur, const float* __restrict__ buz,
                       const float* __restrict__ buh, const float* __restrict__ brR,
                       const float* __restrict__ bzR, const float* __restrict__ bhR,
                       float* __restrict__ bias0, float* __restrict__ bias1) {
  int j = blockIdx.x * 256 + threadIdx.x;  // 0..3071
  int seg = j >> 10, col = j & 1023;
  float b0, b1;
  if (seg == 0)      { b0 = bur[col]; b1 = brR[col] + bur[H_ + col]; }
  else if (seg == 1) { b0 = buz[col]; b1 = bzR[col] + buz[H_ + col]; }
  else               { b0 = buh[col]; b1 = bhR[col] + buh[H_ + col]; }
  bias0[j] = b0; bias1[j] = b1;
}

__global__ void k_init(const float* __restrict__ hidden, u16* __restrict__ hist0,
                       u16* __restrict__ hist1, float* __restrict__ h0f,
                       float* __restrict__ h1f) {
  int i = blockIdx.x * 256 + threadIdx.x;  // 0..65535
  float v0 = hidden[i];
  float v1 = hidden[B_ * H_ + i];
  hist0[i] = f2bf(v0); h0f[i] = v0;
  hist1[i] = f2bf(v1); h1f[i] = v1;
}

// ---------------- bulk GEMM: C[M,N] = A[M,K]bf16 @ Wt[N,K]bf16^T + bias, fp32 out ----------------
// block 256 thr (4 waves as 2x2), tile 128x128, wave tile 64x64 (4x4 frags 16x16, K-step 32)

template <int K>
__global__ __launch_bounds__(256, 2) void k_gemm(const u16* __restrict__ A,
                                                 const u16* __restrict__ Wt,
                                                 const float* __restrict__ bias,
                                                 float* __restrict__ C, int N) {
  const int m0 = blockIdx.x * 128;
  const int n0 = blockIdx.y * 128;
  const int wid = threadIdx.x >> 6;
  const int lane = threadIdx.x & 63;
  const int wm = wid >> 1, wn = wid & 1;
  const int lrow = lane & 15, lk = (lane >> 4) * 8;

  f32x4 acc[4][4] = {};
  const u16* Abase = A + (size_t)(m0 + wm * 64 + lrow) * K + lk;
  const u16* Wbase = Wt + (size_t)(n0 + wn * 64 + lrow) * K + lk;
  bool nvalid[4];
#pragma unroll
  for (int f = 0; f < 4; f++) nvalid[f] = (n0 + wn * 64 + f * 16 + lrow) < N;
  const short8v zv = {};

  for (int ks = 0; ks < K; ks += 32) {
    short8v a[4], b[4];
#pragma unroll
    for (int f = 0; f < 4; f++) a[f] = *(const short8v*)(Abase + (size_t)f * 16 * K + ks);
#pragma unroll
    for (int f = 0; f < 4; f++)
      b[f] = nvalid[f] ? *(const short8v*)(Wbase + (size_t)f * 16 * K + ks) : zv;
#pragma unroll
    for (int i = 0; i < 4; i++)
#pragma unroll
      for (int j = 0; j < 4; j++) acc[i][j] = mfma_bf16(a[i], b[j], acc[i][j]);
  }

  const int drow0 = (lane >> 4) * 4, dcol = lane & 15;
#pragma unroll
  for (int i = 0; i < 4; i++)
#pragma unroll
    for (int j = 0; j < 4; j++) {
      int col = n0 + wn * 64 + j * 16 + dcol;
      if (col >= N) continue;
      float bv = bias[col];
#pragma unroll
      for (int v = 0; v < 4; v++) {
        int row = m0 + wm * 64 + i * 16 + drow0 + v;
        C[(size_t)row * N + col] = acc[i][j][v] + bv;
      }
    }
}

// ---------------- serial recurrence (one layer, all T steps) ----------------
// 64 blocks x 256 thr. Stage A: 2048 cols (r|z) -> 32/block. Stage B: 1024 cols -> 16/block.
// Waves split K (256 each), LDS reduce. Custom device barrier between stages.

__device__ inline void gbar(int* bar, int* phase) {
  __syncthreads();
  if (threadIdx.x == 0) {
    __threadfence();  // release all prior global writes
    int target = 64 * (++(*phase));
    __hip_atomic_fetch_add(bar, 1, __ATOMIC_RELEASE, __HIP_MEMORY_SCOPE_AGENT);
    while (__hip_atomic_load(bar, __ATOMIC_RELAXED, __HIP_MEMORY_SCOPE_AGENT) < target) {
      __builtin_amdgcn_s_sleep(2);
    }
    __threadfence();  // acquire: invalidate caches before consuming peers' data
  }
  __syncthreads();
}

__global__ __launch_bounds__(256) void k_recur(const u16* __restrict__ Ucat,
                                               const float* __restrict__ X,
                                               u16* __restrict__ hist,
                                               float* __restrict__ hf,
                                               u16* __restrict__ rh,
                                               float* __restrict__ zbuf,
                                               int* __restrict__ bar,
                                               float* __restrict__ hfinal_out) {
  __shared__ float red[4][64][32];  // 32 KiB
  const int bid = blockIdx.x;
  const int wid = threadIdx.x >> 6;
  const int lane = threadIdx.x & 63;
  const int lrow = lane & 15, lk = (lane >> 4) * 8;
  const int drow0 = (lane >> 4) * 4, dcol = lane & 15;
  int phase = 0;

  for (int t = 0; t < T_; t++) {
    const u16* hcur = hist + (size_t)t * (B_ * H_);
    // ---------- stage A: r and z gates ----------
    {
      const int j0 = bid * 32;  // in [0, 2048)
      f32x4 acc[4][2] = {};
      const int kbase = wid * 256;
      const u16* Ab = hcur + lrow * H_ + kbase + lk;
      const u16* Bb = Ucat + (size_t)(j0 + lrow) * H_ + kbase + lk;
      for (int kk = 0; kk < 256; kk += 32) {
        short8v a[4], b[2];
#pragma unroll
        for (int f = 0; f < 4; f++) a[f] = *(const short8v*)(Ab + f * 16 * H_ + kk);
#pragma unroll
        for (int f = 0; f < 2; f++) b[f] = *(const short8v*)(Bb + f * 16 * H_ + kk);
#pragma unroll
        for (int i = 0; i < 4; i++)
#pragma unroll
          for (int j = 0; j < 2; j++) acc[i][j] = mfma_bf16(a[i], b[j], acc[i][j]);
      }
#pragma unroll
      for (int i = 0; i < 4; i++)
#pragma unroll
        for (int j = 0; j < 2; j++)
#pragma unroll
          for (int v = 0; v < 4; v++)
            red[wid][i * 16 + drow0 + v][j * 16 + dcol] = acc[i][j][v];
      __syncthreads();
      for (int e = threadIdx.x; e < 2048; e += 256) {
        int row = e >> 5, col = e & 31;
        float s = red[0][row][col] + red[1][row][col] + red[2][row][col] + red[3][row][col];
        int j = j0 + col;
        s += X[((size_t)t * B_ + row) * 3072 + j];
        float sig = 1.f / (1.f + __expf(-s));
        if (j < H_) {
          float hv = hf[row * H_ + j];
          rh[row * H_ + j] = f2bf(sig * hv);
        } else {
          zbuf[row * H_ + (j - H_)] = sig;
        }
      }
    }
    gbar(bar, &phase);
    // ---------- stage B: candidate + state update ----------
    {
      const int j0 = bid * 16;  // in [0, 1024)
      f32x4 acc[4] = {};
      const int kbase = wid * 256;
      const u16* Ab = rh + lrow * H_ + kbase + lk;
      const u16* Bb = Ucat + (size_t)(2048 + j0 + lrow) * H_ + kbase + lk;
      for (int kk = 0; kk < 256; kk += 32) {
        short8v b = *(const short8v*)(Bb + kk);
#pragma unroll
        for (int f = 0; f < 4; f++) {
          short8v a = *(const short8v*)(Ab + f * 16 * H_ + kk);
          acc[f] = mfma_bf16(a, b, acc[f]);
        }
      }
#pragma unroll
      for (int i = 0; i < 4; i++)
#pragma unroll
        for (int v = 0; v < 4; v++) red[wid][i * 16 + drow0 + v][dcol] = acc[i][v];
      __syncthreads();
      for (int e = threadIdx.x; e < 1024; e += 256) {
        int row = e >> 4, col = e & 15;
        float s = red[0][row][col] + red[1][row][col] + red[2][row][col] + red[3][row][col];
        int j = j0 + col;
        s += X[((size_t)t * B_ + row) * 3072 + 2048 + j];
        float th = tanhf(s);
        float z = zbuf[row * H_ + j];
        float hv = hf[row * H_ + j];
        float hn = (1.f - z) * hv + z * th;
        hf[row * H_ + j] = hn;
        hist[(size_t)(t + 1) * (B_ * H_) + row * H_ + j] = f2bf(hn);
        if (t == T_ - 1) hfinal_out[row * H_ + j] = hn;
      }
    }
    gbar(bar, &phase);
  }
}

// ---------------- launcher ----------------

extern "C" void kernel_launch(void* const* d_in, const int* in_sizes, int n_in,
                              void* d_out, int out_size, void* d_ws, size_t ws_size,
                              hipStream_t stream) {
  const int* inputs = (const int*)d_in[0];
  const float* hidden = (const float*)d_in[1];
  const float* emb = (const float*)d_in[2];
  const float* Wr0 = (const float*)d_in[3];
  const float* Wz0 = (const float*)d_in[4];
  const float* Wh0 = (const float*)d_in[5];
  const float* WrR = (const float*)d_in[6];
  const float* WzR = (const float*)d_in[7];
  const float* WhR = (const float*)d_in[8];
  const float* brR = (const float*)d_in[9];
  const float* bzR = (const float*)d_in[10];
  const float* bhR = (const float*)d_in[11];
  const float* Ur = (const float*)d_in[12];
  const float* Uz = (const float*)d_in[13];
  const float* Uh = (const float*)d_in[14];
  const float* bur = (const float*)d_in[15];
  const float* buz = (const float*)d_in[16];
  const float* buh = (const float*)d_in[17];
  const float* Wout = (const float*)d_in[18];
  const float* bout = (const float*)d_in[19];
  float* out = (float*)d_out;

  char* ws = (char*)d_ws;
  size_t off = 0;
  auto alloc = [&](size_t bytes) -> void* {
    void* p = ws + off;
    off += (bytes + 255) & ~(size_t)255;
    return p;
  };
  u16* x_bf   = (u16*)alloc((size_t)TB * E_ * 2);           // 4 MB
  u16* W0cat  = (u16*)alloc((size_t)3072 * 512 * 2);        // 3 MB
  u16* W1cat  = (u16*)alloc((size_t)3072 * 1024 * 2);       // 6 MB
  u16* U0cat  = (u16*)alloc((size_t)3072 * 1024 * 2);       // 6 MB
  u16* U1cat  = (u16*)alloc((size_t)3072 * 1024 * 2);       // 6 MB
  u16* Woutb  = (u16*)alloc((size_t)V_ * H_ * 2);           // 20.5 MB
  float* bias0 = (float*)alloc(3072 * 4);
  float* bias1 = (float*)alloc(3072 * 4);
  float* Xbuf  = (float*)alloc((size_t)TB * 3072 * 4);      // 50 MB (shared by both layers)
  u16* hist0  = (u16*)alloc((size_t)(T_ + 1) * B_ * H_ * 2);// 8.5 MB
  u16* hist1  = (u16*)alloc((size_t)(T_ + 1) * B_ * H_ * 2);// 8.5 MB
  float* hf0 = (float*)alloc((size_t)B_ * H_ * 4);
  float* hf1 = (float*)alloc((size_t)B_ * H_ * 4);
  u16* rhb = (u16*)alloc((size_t)B_ * H_ * 2);
  float* zb = (float*)alloc((size_t)B_ * H_ * 4);
  int* bar = (int*)alloc(256);
  (void)ws_size; (void)in_sizes; (void)n_in; (void)out_size;

  hipMemsetAsync(bar, 0, 8, stream);

  auto conv = [&](const float* s, u16* d, int n) {
    int blocks = (n + 255) / 256;
    if (blocks > 1024) blocks = 1024;
    k_f2bf<<<blocks, 256, 0, stream>>>(s, d, n);
  };
  const int HH = H_ * H_;      // 1,048,576
  const int HE = H_ * E_;      // 524,288
  conv(Wr0, W0cat, HE);
  conv(Wz0, W0cat + HE, HE);
  conv(Wh0, W0cat + 2 * HE, HE);
  conv(WrR, W1cat, HH);
  conv(WzR, W1cat + HH, HH);
  conv(WhR, W1cat + 2 * HH, HH);
  conv(Ur, U0cat, HH);
  conv(Uz, U0cat + HH, HH);
  conv(Uh, U0cat + 2 * HH, HH);
  conv(Ur + HH, U1cat, HH);
  conv(Uz + HH, U1cat + HH, HH);
  conv(Uh + HH, U1cat + 2 * HH, HH);
  conv(Wout, Woutb, V_ * H_);

  k_gather<<<TB * E_ / 256, 256, 0, stream>>>(inputs, emb, x_bf);
  k_bias<<<12, 256, 0, stream>>>(bur, buz, buh, brR, bzR, bhR, bias0, bias1);
  k_init<<<256, 256, 0, stream>>>(hidden, hist0, hist1, hf0, hf1);

  // phase 1: X = x_emb @ [Wr0|Wz0|Wh0]^T + [bur0|buz0|buh0]
  k_gemm<512><<<dim3(32, 24), 256, 0, stream>>>(x_bf, W0cat, bias0, Xbuf, 3072);
  // layer-0 recurrence
  k_recur<<<64, 256, 0, stream>>>(U0cat, Xbuf, hist0, hf0, rhb, zb, bar + 0,
                                  out + (size_t)TB * V_);
  // phase 3: X = h0_hist @ [WrR|WzR|WhR]^T + (brR+bur1 | ...)
  k_gemm<1024><<<dim3(32, 24), 256, 0, stream>>>(hist0 + B_ * H_, W1cat, bias1, Xbuf, 3072);
  // layer-1 recurrence
  k_recur<<<64, 256, 0, stream>>>(U1cat, Xbuf, hist1, hf1, rhb, zb, bar + 1,
                                  out + (size_t)TB * V_ + B_ * H_);
  // phase 5: logits = h1_hist @ Wout^T + bout
  k_gemm<1024><<<dim3(32, 79), 256, 0, stream>>>(hist1 + B_ * H_, Woutb, bout, out, V_);
}

// Round 2
// 2202.542 us; speedup vs baseline: 1.9754x; 1.9754x over previous
//
#include <hip/hip_runtime.h>
#include <hip/hip_bf16.h>

#define T_ 64
#define B_ 64
#define E_ 512
#define H_ 1024
#define V_ 10000
#define TB 4096   // T_*B_
#define BH 65536  // B_*H_

typedef unsigned short u16;
typedef unsigned int u32;
typedef __attribute__((ext_vector_type(8))) short short8v;
typedef __attribute__((ext_vector_type(4))) float f32x4;

__device__ inline f32x4 mfma_bf16(short8v a, short8v b, f32x4 c) {
  return __builtin_amdgcn_mfma_f32_16x16x32_bf16(a, b, c, 0, 0, 0);
}

__device__ inline u16 f2bf(float f) {
  unsigned u = __float_as_uint(f);
  unsigned r = (u + 0x7fffu + ((u >> 16) & 1u)) >> 16;
  return (u16)r;
}
__device__ inline float bf2f(u16 h) { return __uint_as_float(((unsigned)h) << 16); }

// ---------------- prep kernels ----------------

__global__ void k_f2bf(const float* __restrict__ src, u16* __restrict__ dst, int n) {
  int i = blockIdx.x * 256 + threadIdx.x;
  int stride = gridDim.x * 256;
  for (; i < n; i += stride) dst[i] = f2bf(src[i]);
}

__global__ void k_gather(const int* __restrict__ idx, const float* __restrict__ emb,
                         u16* __restrict__ xbf) {
  int i = blockIdx.x * 256 + threadIdx.x;  // over TB*E_
  int row = i >> 9, e = i & 511;
  xbf[i] = f2bf(emb[(size_t)idx[row] * E_ + e]);
}

// fused layer-1 weights: U1W[j][k] = (k<1024) ? U*[1][jj][k] : W*R[0][jj][k-1024]
__global__ void k_pack1(const float* __restrict__ Ur, const float* __restrict__ Uz,
                        const float* __restrict__ Uh, const float* __restrict__ WrR,
                        const float* __restrict__ WzR, const float* __restrict__ WhR,
                        u16* __restrict__ U1W) {
  size_t i = (size_t)blockIdx.x * 256 + threadIdx.x;  // 3072*2048
  int j = (int)(i >> 11);
  int k = (int)(i & 2047);
  int g = j >> 10, jj = j & 1023;
  const float* Usrc = (g == 0) ? Ur : (g == 1 ? Uz : Uh);
  const float* Wsrc = (g == 0) ? WrR : (g == 1 ? WzR : WhR);
  float v = (k < 1024) ? Usrc[(size_t)(H_ * H_) + (size_t)jj * 1024 + k]
                       : Wsrc[(size_t)jj * 1024 + (k - 1024)];
  U1W[i] = f2bf(v);
}

__global__ void k_bias(const float* __restrict__ bur, const float* __restrict__ buz,
                       const float* __restrict__ buh, const float* __restrict__ brR,
                       const float* __restrict__ bzR, const float* __restrict__ bhR,
                       float* __restrict__ bias0, float* __restrict__ bias1) {
  int j = blockIdx.x * 256 + threadIdx.x;  // 0..3071
  int seg = j >> 10, col = j & 1023;
  float b0, b1;
  if (seg == 0)      { b0 = bur[col]; b1 = brR[col] + bur[H_ + col]; }
  else if (seg == 1) { b0 = buz[col]; b1 = bzR[col] + buz[H_ + col]; }
  else               { b0 = buh[col]; b1 = bhR[col] + buh[H_ + col]; }
  bias0[j] = b0; bias1[j] = b1;
}

__global__ void k_init(const float* __restrict__ hidden, u16* __restrict__ hist0,
                       u16* __restrict__ hist1) {
  int i = blockIdx.x * 256 + threadIdx.x;  // 0..65535
  hist0[i] = f2bf(hidden[i]);
  hist1[i] = f2bf(hidden[BH + i]);
}

// ---------------- bulk GEMM: C[M,N] = A[M,K]bf16 @ Wt[N,K]^T + bias ----------------
// tile 128x128, 4 waves 2x2, wave 64x64 (4x4 frags), direct global->reg fragments.

template <int K, bool OBF>
__global__ __launch_bounds__(256, 2) void k_gemm(const u16* __restrict__ A,
                                                 const u16* __restrict__ Wt,
                                                 const float* __restrict__ bias,
                                                 void* __restrict__ Cv, int N) {
  const int m0 = blockIdx.x * 128;
  const int n0 = blockIdx.y * 128;
  const int wid = threadIdx.x >> 6;
  const int lane = threadIdx.x & 63;
  const int wm = wid >> 1, wn = wid & 1;
  const int lrow = lane & 15, lk = (lane >> 4) * 8;

  f32x4 acc[4][4] = {};
  const u16* Abase = A + (size_t)(m0 + wm * 64 + lrow) * K + lk;
  const u16* Wbase = Wt + (size_t)(n0 + wn * 64 + lrow) * K + lk;
  bool nvalid[4];
#pragma unroll
  for (int f = 0; f < 4; f++) nvalid[f] = (n0 + wn * 64 + f * 16 + lrow) < N;
  const short8v zv = {};

  for (int ks = 0; ks < K; ks += 32) {
    short8v a[4], b[4];
#pragma unroll
    for (int f = 0; f < 4; f++) a[f] = *(const short8v*)(Abase + (size_t)f * 16 * K + ks);
#pragma unroll
    for (int f = 0; f < 4; f++)
      b[f] = nvalid[f] ? *(const short8v*)(Wbase + (size_t)f * 16 * K + ks) : zv;
#pragma unroll
    for (int i = 0; i < 4; i++)
#pragma unroll
      for (int j = 0; j < 4; j++) acc[i][j] = mfma_bf16(a[i], b[j], acc[i][j]);
  }

  const int drow0 = (lane >> 4) * 4, dcol = lane & 15;
#pragma unroll
  for (int i = 0; i < 4; i++)
#pragma unroll
    for (int j = 0; j < 4; j++) {
      int col = n0 + wn * 64 + j * 16 + dcol;
      if (col >= N) continue;
      float bv = bias[col];
#pragma unroll
      for (int v = 0; v < 4; v++) {
        int row = m0 + wm * 64 + i * 16 + drow0 + v;
        float r = acc[i][j][v] + bv;
        if (OBF) ((u16*)Cv)[(size_t)row * N + col] = f2bf(r);
        else ((float*)Cv)[(size_t)row * N + col] = r;
      }
    }
}

// ---------------- fused 2-layer pipelined recurrence ----------------
// 128 blocks x 256 thr. Blocks 0-63: layer 0 (step t=p); 64-127: layer 1 (t=p-1).
// Per block: 16 output cols. Stage A: r+z gates (2 col-frags). Stage B: candidate + update.
// Cross-block data (hist, rh) -> per-t slabs, written via relaxed agent atomics
// (write-through to coherence point), read via plain vector loads (addresses unique
// per t => reader caches never stale). Barrier: NO threadfence (keeps L2 warm).

__device__ inline void gbar(int* bar, int& phase) {
  asm volatile("s_waitcnt vmcnt(0)" ::: "memory");  // all my sc-stores globally visible
  __syncthreads();
  ++phase;
  const int tid = threadIdx.x;
  const int gbid = blockIdx.x;
  if (tid == 0)
    __hip_atomic_fetch_add(bar + (gbid & 7) * 32, 1, __ATOMIC_RELAXED,
                           __HIP_MEMORY_SCOPE_AGENT);
  if (gbid == 0) {
    if (tid < 64) {
      const int need = 16 * phase;  // 16 blocks per group
      bool done;
      do {
        int c = (tid < 8) ? __hip_atomic_load(bar + tid * 32, __ATOMIC_RELAXED,
                                              __HIP_MEMORY_SCOPE_AGENT)
                          : need;
        done = __all(c >= need);
        if (!done) __builtin_amdgcn_s_sleep(1);
      } while (!done);
      if (tid == 0)
        __hip_atomic_store(bar + 512, phase, __ATOMIC_RELAXED, __HIP_MEMORY_SCOPE_AGENT);
    }
  } else if (tid == 0) {
    while (__hip_atomic_load(bar + 512, __ATOMIC_RELAXED, __HIP_MEMORY_SCOPE_AGENT) < phase)
      __builtin_amdgcn_s_sleep(1);
  }
  __syncthreads();
}

__global__ __launch_bounds__(256, 1) void k_recur2(
    const u16* __restrict__ U0,      // [3072][1024]
    const u16* __restrict__ U1W,     // [3072][2048]
    const u16* __restrict__ Xb,      // [4096][3072] bf16, layer-0 pre-act (bias folded)
    const float* __restrict__ bias1, // [3072]
    const float* __restrict__ hidden,// [2][64][1024] fp32
    u16* __restrict__ hist0,         // [65][64][1024]
    u16* __restrict__ hist1,
    u16* __restrict__ rh0,           // [64][64][1024]
    u16* __restrict__ rh1,
    int* __restrict__ bar,
    float* __restrict__ hfin) {      // [2][64][1024]
  __shared__ float redA[4 * 64 * 34];  // stage A [4][64][34]; stage B overlays [4][64][18]
  __shared__ float zs[64][16];
  __shared__ float hfs[64][16];

  const int tid = threadIdx.x;
  const int gbid = blockIdx.x;
  const int lay = gbid >> 6;
  const int bid = gbid & 63;
  const int wid = tid >> 6, lane = tid & 63;
  const int lrow = lane & 15, lk = (lane >> 4) * 8;
  const int drow0 = (lane >> 4) * 4, dcol = lane & 15;
  const int jr = bid * 16;
  const int KL = lay ? 2048 : 1024;
  const int KW = KL >> 2;
  const u16* Wg = lay ? U1W : U0;
  u16* histL = lay ? hist1 : hist0;
  u16* rhL = lay ? rh1 : rh0;

  for (int e = tid; e < 1024; e += 256) {
    int row = e >> 4, c = e & 15;
    hfs[row][c] = hidden[(size_t)lay * BH + (size_t)row * 1024 + jr + c];
  }

  const u16* Wr = Wg + (size_t)(jr + lrow) * KL + wid * KW + lk;
  const u16* Wz = Wg + (size_t)(1024 + jr + lrow) * KL + wid * KW + lk;
  const u16* Wh = Wg + (size_t)(2048 + jr + lrow) * KL + wid * KW + lk;

  int phase = 0;
  for (int p = 0; p <= 64; p++) {
    const int t = lay ? (p - 1) : p;
    const bool act = (t >= 0) && (t < T_);
    if (act) {
      // ---------- stage A: r,z gates ----------
      const u16* Aa;
      if (!lay)
        Aa = hist0 + (size_t)t * BH + wid * KW + (size_t)lrow * 1024 + lk;
      else
        Aa = (wid < 2) ? hist1 + (size_t)t * BH + wid * 512 + (size_t)lrow * 1024 + lk
                       : hist0 + (size_t)(t + 1) * BH + (wid - 2) * 512 +
                             (size_t)lrow * 1024 + lk;
      f32x4 acc[4][2] = {};
      for (int kk = 0; kk < KW; kk += 32) {
        short8v b0 = *(const short8v*)(Wr + kk);
        short8v b1 = *(const short8v*)(Wz + kk);
#pragma unroll
        for (int f = 0; f < 4; f++) {
          short8v a = *(const short8v*)(Aa + (size_t)f * 16 * 1024 + kk);
          acc[f][0] = mfma_bf16(a, b0, acc[f][0]);
          acc[f][1] = mfma_bf16(a, b1, acc[f][1]);
        }
      }
#pragma unroll
      for (int i = 0; i < 4; i++)
#pragma unroll
        for (int j = 0; j < 2; j++)
#pragma unroll
          for (int v = 0; v < 4; v++)
            redA[(wid * 64 + i * 16 + drow0 + v) * 34 + j * 16 + dcol] = acc[i][j][v];
      __syncthreads();
      for (int e = tid; e < 1024; e += 256) {
        int half = e >> 9, idx = e & 511, row = idx & 63, pc = idx >> 6;
        int c0 = half * 16 + 2 * pc;
        float s0 = redA[(0 * 64 + row) * 34 + c0] + redA[(1 * 64 + row) * 34 + c0] +
                   redA[(2 * 64 + row) * 34 + c0] + redA[(3 * 64 + row) * 34 + c0];
        float s1 = redA[(0 * 64 + row) * 34 + c0 + 1] + redA[(1 * 64 + row) * 34 + c0 + 1] +
                   redA[(2 * 64 + row) * 34 + c0 + 1] + redA[(3 * 64 + row) * 34 + c0 + 1];
        int j = jr + 2 * pc;
        if (!lay) {
          u32 xp = *(const u32*)(Xb + ((size_t)t * 64 + row) * 3072 + half * 1024 + j);
          s0 += bf2f((u16)(xp & 0xffff)); s1 += bf2f((u16)(xp >> 16));
        } else {
          s0 += bias1[half * 1024 + j]; s1 += bias1[half * 1024 + j + 1];
        }
        float g0 = 1.f / (1.f + __expf(-s0));
        float g1 = 1.f / (1.f + __expf(-s1));
        if (half == 0) {
          u32 hp = *(const u32*)(histL + (size_t)t * BH + (size_t)row * 1024 + j);
          u32 pk = (u32)f2bf(g0 * bf2f((u16)(hp & 0xffff))) |
                   ((u32)f2bf(g1 * bf2f((u16)(hp >> 16))) << 16);
          __hip_atomic_store((u32*)(rhL + (size_t)t * BH + (size_t)row * 1024 + j), pk,
                             __ATOMIC_RELAXED, __HIP_MEMORY_SCOPE_AGENT);
        } else {
          zs[row][2 * pc] = g0; zs[row][2 * pc + 1] = g1;
        }
      }
    }
    gbar(bar, phase);
    if (act) {
      // ---------- stage B: candidate + state update ----------
      const u16* Ab;
      if (!lay)
        Ab = rh0 + (size_t)t * BH + wid * KW + (size_t)lrow * 1024 + lk;
      else
        Ab = (wid < 2) ? rh1 + (size_t)t * BH + wid * 512 + (size_t)lrow * 1024 + lk
                       : hist0 + (size_t)(t + 1) * BH + (wid - 2) * 512 +
                             (size_t)lrow * 1024 + lk;
      f32x4 acc[4] = {};
      for (int kk = 0; kk < KW; kk += 32) {
        short8v b = *(const short8v*)(Wh + kk);
#pragma unroll
        for (int f = 0; f < 4; f++) {
          short8v a = *(const short8v*)(Ab + (size_t)f * 16 * 1024 + kk);
          acc[f] = mfma_bf16(a, b, acc[f]);
        }
      }
#pragma unroll
      for (int i = 0; i < 4; i++)
#pragma unroll
        for (int v = 0; v < 4; v++)
          redA[(wid * 64 + i * 16 + drow0 + v) * 18 + dcol] = acc[i][v];
      __syncthreads();
      for (int e = tid; e < 512; e += 256) {
        int row = e & 63, pc = e >> 6;
        int c0 = 2 * pc;
        float s0 = redA[(0 * 64 + row) * 18 + c0] + redA[(1 * 64 + row) * 18 + c0] +
                   redA[(2 * 64 + row) * 18 + c0] + redA[(3 * 64 + row) * 18 + c0];
        float s1 = redA[(0 * 64 + row) * 18 + c0 + 1] + redA[(1 * 64 + row) * 18 + c0 + 1] +
                   redA[(2 * 64 + row) * 18 + c0 + 1] + redA[(3 * 64 + row) * 18 + c0 + 1];
        int j = jr + c0;
        if (!lay) {
          u32 xp = *(const u32*)(Xb + ((size_t)t * 64 + row) * 3072 + 2048 + j);
          s0 += bf2f((u16)(xp & 0xffff)); s1 += bf2f((u16)(xp >> 16));
        } else {
          s0 += bias1[2048 + j]; s1 += bias1[2048 + j + 1];
        }
        float th0 = tanhf(s0), th1 = tanhf(s1);
        float z0 = zs[row][c0], z1 = zs[row][c0 + 1];
        float h0 = hfs[row][c0], h1 = hfs[row][c0 + 1];
        float hn0 = (1.f - z0) * h0 + z0 * th0;
        float hn1 = (1.f - z1) * h1 + z1 * th1;
        hfs[row][c0] = hn0; hfs[row][c0 + 1] = hn1;
        u32 pk = (u32)f2bf(hn0) | ((u32)f2bf(hn1) << 16);
        __hip_atomic_store((u32*)(histL + (size_t)(t + 1) * BH + (size_t)row * 1024 + j),
                           pk, __ATOMIC_RELAXED, __HIP_MEMORY_SCOPE_AGENT);
        if (t == T_ - 1) {
          hfin[(size_t)lay * BH + (size_t)row * 1024 + j] = hn0;
          hfin[(size_t)lay * BH + (size_t)row * 1024 + j + 1] = hn1;
        }
      }
    }
    gbar(bar, phase);
  }
}

// ---------------- launcher ----------------

extern "C" void kernel_launch(void* const* d_in, const int* in_sizes, int n_in,
                              void* d_out, int out_size, void* d_ws, size_t ws_size,
                              hipStream_t stream) {
  const int* inputs = (const int*)d_in[0];
  const float* hidden = (const float*)d_in[1];
  const float* emb = (const float*)d_in[2];
  const float* Wr0 = (const float*)d_in[3];
  const float* Wz0 = (const float*)d_in[4];
  const float* Wh0 = (const float*)d_in[5];
  const float* WrR = (const float*)d_in[6];
  const float* WzR = (const float*)d_in[7];
  const float* WhR = (const float*)d_in[8];
  const float* brR = (const float*)d_in[9];
  const float* bzR = (const float*)d_in[10];
  const float* bhR = (const float*)d_in[11];
  const float* Ur = (const float*)d_in[12];
  const float* Uz = (const float*)d_in[13];
  const float* Uh = (const float*)d_in[14];
  const float* bur = (const float*)d_in[15];
  const float* buz = (const float*)d_in[16];
  const float* buh = (const float*)d_in[17];
  const float* Wout = (const float*)d_in[18];
  const float* bout = (const float*)d_in[19];
  float* out = (float*)d_out;

  char* ws = (char*)d_ws;
  size_t off = 0;
  auto alloc = [&](size_t bytes) -> void* {
    void* p = ws + off;
    off += (bytes + 255) & ~(size_t)255;
    return p;
  };
  u16* x_bf  = (u16*)alloc((size_t)TB * E_ * 2);            // 4 MB
  u16* W0cat = (u16*)alloc((size_t)3072 * 512 * 2);         // 3 MB
  u16* U0cat = (u16*)alloc((size_t)3072 * 1024 * 2);        // 6 MB
  u16* U1W   = (u16*)alloc((size_t)3072 * 2048 * 2);        // 12.6 MB
  u16* Woutb = (u16*)alloc((size_t)V_ * H_ * 2);            // 20.5 MB
  float* bias0 = (float*)alloc(3072 * 4);
  float* bias1 = (float*)alloc(3072 * 4);
  u16* Xbuf  = (u16*)alloc((size_t)TB * 3072 * 2);          // 25 MB (bf16 pre-act)
  u16* hist0 = (u16*)alloc((size_t)(T_ + 1) * BH * 2);      // 8.5 MB
  u16* hist1 = (u16*)alloc((size_t)(T_ + 1) * BH * 2);      // 8.5 MB
  u16* rh0   = (u16*)alloc((size_t)T_ * BH * 2);            // 8.4 MB
  u16* rh1   = (u16*)alloc((size_t)T_ * BH * 2);            // 8.4 MB
  int* bar   = (int*)alloc(4096);
  (void)ws_size; (void)in_sizes; (void)n_in; (void)out_size;

  hipMemsetAsync(bar, 0, 4096, stream);

  auto conv = [&](const float* s, u16* d, int n) {
    int blocks = (n + 255) / 256;
    if (blocks > 1024) blocks = 1024;
    k_f2bf<<<blocks, 256, 0, stream>>>(s, d, n);
  };
  const int HH = H_ * H_;
  const int HE = H_ * E_;
  conv(Wr0, W0cat, HE);
  conv(Wz0, W0cat + HE, HE);
  conv(Wh0, W0cat + 2 * HE, HE);
  conv(Ur, U0cat, HH);
  conv(Uz, U0cat + HH, HH);
  conv(Uh, U0cat + 2 * HH, HH);
  conv(Wout, Woutb, V_ * H_);
  k_pack1<<<(3072 * 2048) / 256, 256, 0, stream>>>(Ur, Uz, Uh, WrR, WzR, WhR, U1W);

  k_gather<<<TB * E_ / 256, 256, 0, stream>>>(inputs, emb, x_bf);
  k_bias<<<12, 256, 0, stream>>>(bur, buz, buh, brR, bzR, bhR, bias0, bias1);
  k_init<<<256, 256, 0, stream>>>(hidden, hist0, hist1);

  // layer-0 input projections (bias folded), bf16 output
  k_gemm<512, true><<<dim3(32, 24), 256, 0, stream>>>(x_bf, W0cat, bias0, Xbuf, 3072);
  // fused pipelined 2-layer recurrence
  k_recur2<<<128, 256, 0, stream>>>(U0cat, U1W, Xbuf, bias1, hidden, hist0, hist1,
                                    rh0, rh1, bar, out + (size_t)TB * V_);
  // logits = h1_hist @ Wout^T + bout
  k_gemm<1024, false><<<dim3(32, 79), 256, 0, stream>>>(hist1 + BH, Woutb, bout, out, V_);
}